// Round 1
// baseline (212.015 us; speedup 1.0000x reference)
//
#include <hip/hip_runtime.h>

#define VOLD 256
#define WWIN 32

__global__ __launch_bounds__(256) void gauss_splat_kernel(
    const float* __restrict__ centers,   // (N,3) normalized
    const float* __restrict__ sigmas,    // (N,)
    const float* __restrict__ intens,    // (N,)
    float* __restrict__ vol,             // 256^3 fp32, pre-zeroed
    int N)
{
    const int g = blockIdx.x;
    if (g >= N) return;
    const int t = threadIdx.x;

    __shared__ float ew[3][WWIN];   // per-axis exp weights (0 where masked)
    __shared__ int   sstart[3];     // per-axis window start

    const float scale = 255.0f;
    const float sig   = sigmas[g];
    const float I     = intens[g];
    const float cut   = 3.0f * sig * scale;
    const float inv2s2 = 0.5f / (sig * sig);

    if (t < 96) {
        const int axis = t >> 5;        // 0,1,2
        const int o    = t & 31;        // 0..31
        const float cn = centers[3 * g + axis];   // normalized center
        const float cv = cn * scale;              // voxel-space center
        const float minf = fmaxf(cv - cut, 0.0f);
        const float maxf = fminf(cv + cut, scale);
        const int mini = (int)floorf(minf);
        const int maxi = min((int)floorf(maxf) + 1, VOLD);
        const int st   = min(max(mini, 0), VOLD - WWIN);
        const int idx  = st + o;
        const bool valid = (idx >= mini) && (idx < maxi);
        const float pos = (float)idx / scale;     // normalized grid coord
        const float d   = pos - cn;
        ew[axis][o] = valid ? __expf(-d * d * inv2s2) : 0.0f;
        if (o == 0) sstart[axis] = st;
    }
    __syncthreads();

    const int bx = sstart[0], by = sstart[1], bz = sstart[2];

    const int z  = t & 31;        // lane-contiguous z => coalesced atomics
    const int r0 = t >> 5;        // 0..7 (y phase)
    const float ezI = ew[2][z] * I;
    if (ezI == 0.0f) return;      // whole z-column masked for this thread

    // Base linear index for (bx, by, bz+z)
    const int baseLin = bx * (VOLD * VOLD) + by * VOLD + bz + z;

    for (int x = 0; x < WWIN; ++x) {
        const float exv = ew[0][x];     // block-uniform
        if (exv == 0.0f) continue;      // uniform skip of masked x-planes
        const float exz = exv * ezI;
        const int linX = baseLin + x * (VOLD * VOLD);
        #pragma unroll
        for (int yy = 0; yy < WWIN / 8; ++yy) {
            const int y = r0 + yy * 8;
            const float v = exz * ew[1][y];
            if (v != 0.0f) {
                atomicAdd(&vol[linX + y * VOLD], v);
            }
        }
    }
}

extern "C" void kernel_launch(void* const* d_in, const int* in_sizes, int n_in,
                              void* d_out, int out_size, void* d_ws, size_t ws_size,
                              hipStream_t stream) {
    const float* centers = (const float*)d_in[0];   // (N,3)
    const float* sigmas  = (const float*)d_in[1];   // (N,)
    const float* intens  = (const float*)d_in[2];   // (N,)
    float* vol = (float*)d_out;
    const int N = in_sizes[1];                      // 4000

    // Zero the output volume (harness poisons it; we must own initialization).
    hipMemsetAsync(vol, 0, (size_t)out_size * sizeof(float), stream);

    gauss_splat_kernel<<<N, 256, 0, stream>>>(centers, sigmas, intens, vol, N);
}

// Round 2
// 41.920 us; speedup vs baseline: 5.0577x; 5.0577x over previous
//
#include <hip/hip_runtime.h>

#define VOLD   256
#define CDIM   16
#define NC     (VOLD / CDIM)     // 16 cells per axis
#define NCELLS (NC * NC * NC)    // 4096
#define CAP    64                // max gaussians per cell (avg ~11, Poisson tail ~0)

// ---------------- Phase 0: bin gaussians into cells by bbox overlap ----------
__global__ __launch_bounds__(256) void bin_kernel(
    const float* __restrict__ centers, const float* __restrict__ sigmas,
    int* __restrict__ cnt, int* __restrict__ lists, int N)
{
    const int g = blockIdx.x * 256 + threadIdx.x;
    if (g >= N) return;

    const float sig = sigmas[g];
    const float cut = 3.0f * sig * 255.0f;
    int c0[3], c1[3];
    #pragma unroll
    for (int a = 0; a < 3; ++a) {
        const float cv   = centers[3 * g + a] * 255.0f;
        const float minf = fmaxf(cv - cut, 0.0f);
        const float maxf = fminf(cv + cut, 255.0f);
        const int mini = (int)floorf(minf);
        const int maxi = min((int)floorf(maxf) + 1, VOLD);   // exclusive
        c0[a] = mini >> 4;
        c1[a] = (maxi - 1) >> 4;
    }
    for (int cx = c0[0]; cx <= c1[0]; ++cx)
        for (int cy = c0[1]; cy <= c1[1]; ++cy)
            for (int cz = c0[2]; cz <= c1[2]; ++cz) {
                const int cell = (cx * NC + cy) * NC + cz;
                const int p = atomicAdd(&cnt[cell], 1);
                if (p < CAP) lists[cell * CAP + p] = g;
            }
}

// ---------------- Phase 1: per-cell gather, register accumulate, plain store -
__global__ __launch_bounds__(256) void accum_kernel(
    const float* __restrict__ centers, const float* __restrict__ sigmas,
    const float* __restrict__ intens,
    const int* __restrict__ cnt, const int* __restrict__ lists,
    float* __restrict__ vol)
{
    const int cell = blockIdx.x;
    const int cz = (cell & (NC - 1)) * CDIM;
    const int cy = ((cell >> 4) & (NC - 1)) * CDIM;
    const int cx = (cell >> 8) * CDIM;
    const int t  = threadIdx.x;
    const int K  = min(cnt[cell], CAP);

    __shared__ float w[CAP][3][CDIM];   // 12 KB: per-gaussian per-axis weights

    // Weight phase: K*48 items spread over 256 threads.
    for (int i = t; i < K * 48; i += 256) {
        const int g    = i / 48;
        const int r    = i - g * 48;
        const int axis = r >> 4;
        const int o    = r & 15;
        const int gi   = lists[cell * CAP + g];

        const float cn  = centers[3 * gi + axis];
        const float sig = sigmas[gi];
        const float cv  = cn * 255.0f;
        const float cut = 3.0f * sig * 255.0f;
        const float minf = fmaxf(cv - cut, 0.0f);
        const float maxf = fminf(cv + cut, 255.0f);
        const int mini = (int)floorf(minf);
        const int maxi = min((int)floorf(maxf) + 1, VOLD);

        const int base = (axis == 0) ? cx : (axis == 1) ? cy : cz;
        const int idx  = base + o;
        float wv = 0.0f;
        if (idx >= mini && idx < maxi) {
            const float d = (float)idx * (1.0f / 255.0f) - cn;
            const float inv2s2 = 0.5f / (sig * sig);
            wv = __expf(-d * d * inv2s2);
            if (axis == 0) wv *= intens[gi];   // fold intensity into x-weights
        }
        w[g][axis][o] = wv;
    }
    __syncthreads();

    const int tz = t & 15;
    const int ty = t >> 4;

    float acc[CDIM];
    #pragma unroll
    for (int x = 0; x < CDIM; ++x) acc[x] = 0.0f;

    for (int k = 0; k < K; ++k) {
        const float c = w[k][1][ty] * w[k][2][tz];
        if (c != 0.0f) {
            const float4* wx4 = (const float4*)&w[k][0][0];
            #pragma unroll
            for (int q = 0; q < 4; ++q) {
                const float4 v = wx4[q];
                acc[4 * q + 0] += v.x * c;
                acc[4 * q + 1] += v.y * c;
                acc[4 * q + 2] += v.z * c;
                acc[4 * q + 3] += v.w * c;
            }
        }
    }

    // Store the cell (covers the whole volume across blocks; zeros included).
    const size_t base = (size_t)cx * VOLD * VOLD + (size_t)(cy + ty) * VOLD + (size_t)(cz + tz);
    #pragma unroll
    for (int x = 0; x < CDIM; ++x)
        vol[base + (size_t)x * VOLD * VOLD] = acc[x];
}

extern "C" void kernel_launch(void* const* d_in, const int* in_sizes, int n_in,
                              void* d_out, int out_size, void* d_ws, size_t ws_size,
                              hipStream_t stream) {
    const float* centers = (const float*)d_in[0];   // (N,3)
    const float* sigmas  = (const float*)d_in[1];   // (N,)
    const float* intens  = (const float*)d_in[2];   // (N,)
    float* vol = (float*)d_out;
    const int N = in_sizes[1];                      // 4000

    int* cnt   = (int*)d_ws;                        // NCELLS counters
    int* lists = cnt + NCELLS;                      // NCELLS * CAP indices (~1 MB)

    hipMemsetAsync(cnt, 0, NCELLS * sizeof(int), stream);
    bin_kernel<<<(N + 255) / 256, 256, 0, stream>>>(centers, sigmas, cnt, lists, N);
    accum_kernel<<<NCELLS, 256, 0, stream>>>(centers, sigmas, intens, cnt, lists, vol);
}

// Round 3
// 34.761 us; speedup vs baseline: 6.0992x; 1.2059x over previous
//
#include <hip/hip_runtime.h>

#define VOLD   256
#define CDIM   16
#define NC     16
#define NCELLS 4096
#define CAP    64                // max gaussians per cell (avg ~12, +15 sigma tail)

// ---- Phase 0: pack per-gaussian cell-space bbox into one int (4b/coord) ----
__global__ __launch_bounds__(256) void prep_kernel(
    const float* __restrict__ centers, const float* __restrict__ sigmas,
    int* __restrict__ bbox, int N)
{
    const int g = blockIdx.x * 256 + threadIdx.x;
    if (g >= N) return;
    const float sig = sigmas[g];
    const float cut = 3.0f * sig * 255.0f;
    int pack = 0;
    #pragma unroll
    for (int a = 0; a < 3; ++a) {
        const float cv   = centers[3 * g + a] * 255.0f;
        const float minf = fmaxf(cv - cut, 0.0f);
        const float maxf = fminf(cv + cut, 255.0f);
        const int mini = (int)floorf(minf);
        const int maxi = min((int)floorf(maxf) + 1, VOLD);   // exclusive
        const int c0 = mini >> 4;
        const int c1 = (maxi - 1) >> 4;
        pack |= (c0 << (8 * a)) | (c1 << (8 * a + 4));
    }
    bbox[g] = pack;
}

// ---- Phase 1: per-cell self-binning gather + separable accumulate ----------
__global__ __launch_bounds__(256) void splat_kernel(
    const float* __restrict__ centers, const float* __restrict__ sigmas,
    const float* __restrict__ intens, const int* __restrict__ bbox,
    float* __restrict__ vol, int N)
{
    const int cell = blockIdx.x;
    const int czc = cell & 15, cyc = (cell >> 4) & 15, cxc = cell >> 8;
    const int cx = cxc * CDIM, cy = cyc * CDIM, cz = czc * CDIM;
    const int t = threadIdx.x;

    __shared__ int   lcnt;
    __shared__ int   list[CAP];
    __shared__ float w[CAP][3][CDIM];   // 12 KB

    if (t == 0) lcnt = 0;
    __syncthreads();

    // Scan all gaussians' packed bboxes; LDS-compact the hits.
    for (int g = t; g < N; g += 256) {
        const int pk = bbox[g];
        const int x0 = pk & 15,         x1 = (pk >> 4) & 15;
        const int y0 = (pk >> 8) & 15,  y1 = (pk >> 12) & 15;
        const int z0 = (pk >> 16) & 15, z1 = (pk >> 20) & 15;
        if (cxc >= x0 && cxc <= x1 && cyc >= y0 && cyc <= y1 &&
            czc >= z0 && czc <= z1) {
            const int p = atomicAdd(&lcnt, 1);
            if (p < CAP) list[p] = g;
        }
    }
    __syncthreads();
    const int K = min(lcnt, CAP);

    // Weight phase: K*48 separable exp weights.
    for (int i = t; i < K * 48; i += 256) {
        const int g    = i / 48;
        const int r    = i - g * 48;
        const int axis = r >> 4;
        const int o    = r & 15;
        const int gi   = list[g];

        const float cn  = centers[3 * gi + axis];
        const float sig = sigmas[gi];
        const float cv  = cn * 255.0f;
        const float cut = 3.0f * sig * 255.0f;
        const float minf = fmaxf(cv - cut, 0.0f);
        const float maxf = fminf(cv + cut, 255.0f);
        const int mini = (int)floorf(minf);
        const int maxi = min((int)floorf(maxf) + 1, VOLD);

        const int base = (axis == 0) ? cx : (axis == 1) ? cy : cz;
        const int idx  = base + o;
        float wv = 0.0f;
        if (idx >= mini && idx < maxi) {
            const float d = (float)idx * (1.0f / 255.0f) - cn;
            const float inv2s2 = 0.5f / (sig * sig);
            wv = __expf(-d * d * inv2s2);
            if (axis == 0) wv *= intens[gi];   // fold intensity into x-weights
        }
        w[g][axis][o] = wv;
    }
    __syncthreads();

    const int tz = t & 15;
    const int ty = t >> 4;

    float acc[CDIM];
    #pragma unroll
    for (int x = 0; x < CDIM; ++x) acc[x] = 0.0f;

    for (int k = 0; k < K; ++k) {
        const float c = w[k][1][ty] * w[k][2][tz];
        if (c != 0.0f) {
            const float4* wx4 = (const float4*)&w[k][0][0];
            #pragma unroll
            for (int q = 0; q < 4; ++q) {
                const float4 v = wx4[q];
                acc[4 * q + 0] += v.x * c;
                acc[4 * q + 1] += v.y * c;
                acc[4 * q + 2] += v.z * c;
                acc[4 * q + 3] += v.w * c;
            }
        }
    }

    // Full coverage store (zeros included) — no memset of d_out needed.
    const size_t base = (size_t)cx * VOLD * VOLD + (size_t)(cy + ty) * VOLD + (size_t)(cz + tz);
    #pragma unroll
    for (int x = 0; x < CDIM; ++x)
        vol[base + (size_t)x * VOLD * VOLD] = acc[x];
}

extern "C" void kernel_launch(void* const* d_in, const int* in_sizes, int n_in,
                              void* d_out, int out_size, void* d_ws, size_t ws_size,
                              hipStream_t stream) {
    const float* centers = (const float*)d_in[0];   // (N,3)
    const float* sigmas  = (const float*)d_in[1];   // (N,)
    const float* intens  = (const float*)d_in[2];   // (N,)
    float* vol = (float*)d_out;
    const int N = in_sizes[1];                      // 4000

    int* bbox = (int*)d_ws;                         // N packed bboxes (16 KB)

    prep_kernel<<<(N + 255) / 256, 256, 0, stream>>>(centers, sigmas, bbox, N);
    splat_kernel<<<NCELLS, 256, 0, stream>>>(centers, sigmas, intens, bbox, vol, N);
}